// Round 12
// baseline (1651.039 us; speedup 1.0000x reference)
//
#include <hip/hip_runtime.h>

#define N_NODES 50000
#define N_EDGES 800000
#define NBUCK 196       // dst>>8 -> 0..195
#define BCAP 8192       // fixed ebuf region per bucket (mean 4096, sd ~64)
#define NPART ((N_EDGES + 2047) / 2048)   // 391
#define NTILE ((N_NODES + 31) / 32)       // 1563
#define GRID_BLOCKS 768  // co-residency guaranteed: 4 blk/CU x 256 CU = 1024 slots

typedef __attribute__((ext_vector_type(8))) short short8;
typedef __attribute__((ext_vector_type(4))) float f32x4;
typedef __attribute__((ext_vector_type(8))) unsigned short ushort8v;
typedef __attribute__((ext_vector_type(16))) unsigned char uchar16;

// ---------------- helpers ----------------

__device__ inline void split_bf16(float f, unsigned short& hi, unsigned short& lo) {
    union { float f; unsigned u; } a; a.f = f;
    unsigned r = (a.u + 0x7fffu + ((a.u >> 16) & 1u)) >> 16;  // RNE to bf16
    hi = (unsigned short)r;
    union { unsigned u; float f; } b; b.u = r << 16;
    union { float f; unsigned u; } c; c.f = f - b.f;
    unsigned r2 = (c.u + 0x7fffu + ((c.u >> 16) & 1u)) >> 16;
    lo = (unsigned short)r2;
}

__device__ inline unsigned short f2bf(float f) {
    union { float f; unsigned u; } a; a.f = f;
    return (unsigned short)((a.u + 0x7fffu + ((a.u >> 16) & 1u)) >> 16);
}

__device__ inline float bf2f(unsigned short u) {
    union { unsigned u; float f; } a; a.u = (unsigned)u << 16; return a.f;
}

__device__ inline unsigned char q8(float v, float qs) {
    int qi = (int)rintf(v * qs);
    qi = qi > 127 ? 127 : (qi < -127 ? -127 : qi);
    return (unsigned char)(qi + 128);
}

// accumulate 8 biased-u8 values (uint2) scaled by s into a[0..7]
__device__ inline void acc8(float* a, uint2 w, float s) {
#pragma unroll
    for (int j = 0; j < 4; ++j) {
        a[j]     += (float)((w.x >> (8 * j)) & 255u) * s;
        a[j + 4] += (float)((w.y >> (8 * j)) & 255u) * s;
    }
}

// ---------------- device-wide barrier (R12) ----------------
// All GRID_BLOCKS blocks are guaranteed co-resident (static occupancy math),
// so a sense-reversal spin barrier is safe. Agent-scope atomics give the
// cross-XCD release/acquire chain (guide G16): each arriver RELEASEs its
// writes on bar[0]; the last arriver ACQ_RELs (collecting all), then
// RELEASEs gen on bar[1]; waiters ACQUIRE gen -> transitively see all data.

__device__ inline void grid_sync(int* bar) {
    __threadfence();
    __syncthreads();
    if (threadIdx.x == 0) {
        int gen = __hip_atomic_load(&bar[1], __ATOMIC_RELAXED, __HIP_MEMORY_SCOPE_AGENT);
        int prev = __hip_atomic_fetch_add(&bar[0], 1, __ATOMIC_ACQ_REL, __HIP_MEMORY_SCOPE_AGENT);
        if (prev == GRID_BLOCKS - 1) {
            __hip_atomic_store(&bar[0], 0, __ATOMIC_RELAXED, __HIP_MEMORY_SCOPE_AGENT);
            __hip_atomic_fetch_add(&bar[1], 1, __ATOMIC_ACQ_REL, __HIP_MEMORY_SCOPE_AGENT);
        } else {
            int g;
            do {
                __builtin_amdgcn_s_sleep(2);
                g = __hip_atomic_load(&bar[1], __ATOMIC_ACQUIRE, __HIP_MEMORY_SCOPE_AGENT);
            } while (g == gen);
        }
    }
    __syncthreads();
}

// ---------------- phase bodies (verbatim R10, blockIdx -> vb) ----------------

__device__ void prep_vb(int vb, int tid,
                        const float* __restrict__ W0, const float* __restrict__ W1,
                        const float* __restrict__ W2, const float* __restrict__ W3,
                        const float* __restrict__ W4, const float* __restrict__ W5,
                        unsigned short* __restrict__ wout,
                        const float* __restrict__ x, unsigned short* __restrict__ xhi,
                        unsigned short* __restrict__ xlo,
                        unsigned char* __restrict__ xq, float* __restrict__ xsc,
                        int* __restrict__ bucketCur) {
    if (vb < 320) {
        int t = vb * 256 + tid;  // 0..81919
        const float* W; int D, local, half; size_t base;
        if (t < 65536) {
            int mat = t >> 14; local = t & 16383; D = 128; half = 16384;
            base = (size_t)mat * 32768;
            W = mat == 0 ? W0 : mat == 1 ? W1 : mat == 2 ? W2 : W3;
        } else {
            int m = (t - 65536) >> 13; local = (t - 65536) & 8191; D = 64; half = 8192;
            base = 131072 + (size_t)m * 16384;
            W = m == 0 ? W4 : W5;
        }
        int j = local & 7, lane = (local >> 3) & 63, ks = (local >> 9) & 3, ct = local >> 11;
        int k = ks * 32 + ((lane >> 4) << 3) + j;
        int n = (ct << 4) + (lane & 15);
        unsigned short hi, lo;
        split_bf16(W[k * D + n], hi, lo);
        wout[base + local] = hi;
        wout[base + half + local] = lo;
    } else if (vb < 1883) {
        int t = (vb - 320) * 256 + tid;          // one 16-float chunk/thread
        if (t < N_NODES * 8) {                   // guard (no return: barrier safety)
            const float* p = x + (size_t)t * 16;
            float4 v0 = *(const float4*)(p);
            float4 v1 = *(const float4*)(p + 4);
            float4 v2 = *(const float4*)(p + 8);
            float4 v3 = *(const float4*)(p + 12);
            float vv[16] = {v0.x, v0.y, v0.z, v0.w, v1.x, v1.y, v1.z, v1.w,
                            v2.x, v2.y, v2.z, v2.w, v3.x, v3.y, v3.z, v3.w};
            float m = 0.f;
#pragma unroll
            for (int j = 0; j < 16; ++j) m = fmaxf(m, fabsf(vv[j]));
            m = fmaxf(m, __shfl_xor(m, 1));
            m = fmaxf(m, __shfl_xor(m, 2));
            m = fmaxf(m, __shfl_xor(m, 4));
            float qs = m > 0.f ? 127.0f / m : 0.0f;
            uchar16 qv;
            ushort8v h0, l0, h1, l1;
#pragma unroll
            for (int j = 0; j < 16; ++j) {
                unsigned short a, b;
                split_bf16(vv[j], a, b);
                if (j < 8) { h0[j] = a; l0[j] = b; } else { h1[j - 8] = a; l1[j - 8] = b; }
                qv[j] = q8(vv[j], qs);
            }
            *(ushort8v*)(xhi + (size_t)t * 16) = h0;
            *(ushort8v*)(xhi + (size_t)t * 16 + 8) = h1;
            *(ushort8v*)(xlo + (size_t)t * 16) = l0;
            *(ushort8v*)(xlo + (size_t)t * 16 + 8) = l1;
            *(uchar16*)(xq + (size_t)t * 16) = qv;
            if ((t & 7) == 0) xsc[t >> 3] = m * (1.0f / 127.0f);
        }
    } else {
        if (tid < 256) bucketCur[tid] = 0;
    }
}

__device__ void partition_vb(int vb, int tid, unsigned char* smem,
                             const int* __restrict__ src, const int* __restrict__ dst,
                             int* __restrict__ bucketCur, unsigned int* __restrict__ ebuf,
                             int E) {
    int* hist = (int*)smem;                 // 196
    int* binoff = hist + NBUCK;             // 196
    int* bincur = binoff + NBUCK;           // 196
    int* runstart = bincur + NBUCK;         // 196
    int* scanbuf = runstart + NBUCK;        // 256
    unsigned int* sortbuf = (unsigned int*)(scanbuf + 256);  // 2048
    const int base = vb * 2048;
    if (tid < NBUCK) hist[tid] = 0;
    __syncthreads();
    int myb[8]; unsigned int myp[8];
#pragma unroll
    for (int i = 0; i < 8; ++i) {
        int e = base + i * 256 + tid;
        if (e < E) {
            int d = dst[e], s = src[e];
            myb[i] = d >> 8;
            myp[i] = ((unsigned)d << 16) | (unsigned)s;
            atomicAdd(&hist[myb[i]], 1);
        } else myb[i] = -1;
    }
    __syncthreads();
    int v = (tid < NBUCK) ? hist[tid] : 0;
    scanbuf[tid] = v;
    __syncthreads();
    for (int off = 1; off < 256; off <<= 1) {
        int t = (tid >= off) ? scanbuf[tid - off] : 0;
        __syncthreads();
        scanbuf[tid] += t;
        __syncthreads();
    }
    if (tid < NBUCK) {
        binoff[tid] = scanbuf[tid] - v;
        bincur[tid] = 0;
        runstart[tid] = tid * BCAP + atomicAdd(&bucketCur[tid], v);
    }
    __syncthreads();
#pragma unroll
    for (int i = 0; i < 8; ++i) {
        if (myb[i] >= 0) {
            int r = atomicAdd(&bincur[myb[i]], 1);
            sortbuf[binoff[myb[i]] + r] = myp[i];
        }
    }
    __syncthreads();
    int nloc = E - base; if (nloc > 2048) nloc = 2048;
#pragma unroll
    for (int i = 0; i < 8; ++i) {
        int idx = i * 256 + tid;
        if (idx < nloc) {
            unsigned int p = sortbuf[idx];
            int b = p >> 24;   // dst>>8
            ebuf[runstart[b] + (idx - binoff[b])] = p;
        }
    }
    __syncthreads();   // LDS reuse safety across grid-stride iterations
}

__device__ void finefill_vb(int b, int tid, unsigned char* smem,
                            const unsigned int* __restrict__ ebuf,
                            const int* __restrict__ bucketCur,
                            int* __restrict__ rowbeg, int* __restrict__ rowend,
                            unsigned short* __restrict__ esrc, int n) {
    int* cnt = (int*)smem;          // 256
    int* scanbuf = cnt + 256;       // 256
    int* cur = scanbuf + 256;       // 256
    const int nbase = b << 8;
    cnt[tid] = 0;
    __syncthreads();
    const int lo = b * BCAP, hi = lo + bucketCur[b];
    for (int k = lo + tid; k < hi; k += 256)
        atomicAdd(&cnt[(ebuf[k] >> 16) & 255], 1);
    __syncthreads();
    int v = cnt[tid];
    scanbuf[tid] = v;
    __syncthreads();
    for (int off = 1; off < 256; off <<= 1) {
        int t = (tid >= off) ? scanbuf[tid - off] : 0;
        __syncthreads();
        scanbuf[tid] += t;
        __syncthreads();
    }
    int start = lo + scanbuf[tid] - v;   // exclusive
    if (nbase + tid < n) { rowbeg[nbase + tid] = start; rowend[nbase + tid] = start + v; }
    cur[tid] = start;
    __syncthreads();
    for (int k = lo + tid; k < hi; k += 256) {
        unsigned int p = ebuf[k];
        int pos = atomicAdd(&cur[(p >> 16) & 255], 1);
        esrc[pos] = (unsigned short)(p & 0xFFFFu);
    }
    __syncthreads();   // LDS reuse safety
}

// ---------------- fused SAGE tile (verbatim R10 256-thread layer) ------------

template <int DOUT, bool RELU, bool SPLIT_OUT>
__device__ void sage_tile(int vb, int tid, unsigned char* smem,
                          const unsigned char* __restrict__ Hq, const float* __restrict__ Hsc,
                          const unsigned short* __restrict__ Hhi, const unsigned short* __restrict__ Hlo,
                          const int* __restrict__ rowbeg, const int* __restrict__ rowend,
                          const unsigned short* __restrict__ esrc,
                          const unsigned short* __restrict__ B1p, const unsigned short* __restrict__ B2p,
                          const float* __restrict__ bias, float* __restrict__ outf,
                          unsigned short* __restrict__ outhi, unsigned short* __restrict__ outlo,
                          unsigned char* __restrict__ outq, float* __restrict__ outsc, int M) {
    constexpr int K = 128, BM = 32, KS = 4, CT = DOUT / 16, CPW = CT / 4;
    constexpr int PITCH = K + 8;
    constexpr int HALF = CT * KS * 512;
    unsigned short* As0 = (unsigned short*)smem;            // agg-hi
    unsigned short* As1 = As0 + BM * PITCH;                 // self-hi
    unsigned short* As2 = As1 + BM * PITCH;                 // self-lo
    float (*wmax)[4] = (float (*)[4])(smem + 3 * BM * PITCH * 2);  // 26112

    const int r0 = vb * BM;

    // ---- Phase A: stage self hi/lo rows (coalesced) ----
    const unsigned short* __restrict__ srcs[2] = {Hhi, Hlo};
    unsigned short* dsts[2] = {As1, As2};
#pragma unroll
    for (int s = 0; s < 2; ++s) {
#pragma unroll
        for (int c = 0; c < 2; ++c) {
            int chunk = tid + c * 256;
            int row = chunk >> 4;
            int c8 = (chunk & 15) * 8;
            int grow = r0 + row; if (grow >= M) grow = M - 1;
            *(ushort8v*)(&dsts[s][row * PITCH + c8]) =
                *(const ushort8v*)(srcs[s] + (size_t)grow * K + c8);
        }
    }

    // ---- Phase B: int8 gather-mean into As0 (R7 loop body, 2 rows/group) ----
    {
        const int g16 = tid >> 4, l16 = tid & 15;
        const unsigned char* __restrict__ Hb = Hq + l16 * 8;
#pragma unroll
        for (int nn = 0; nn < 2; ++nn) {
            int row = g16 * 2 + nn;
            int node = r0 + row; if (node >= M) node = M - 1;  // pad: harmless dup
            int beg = rowbeg[node], end = rowend[node];
            float a0[8] = {0,0,0,0,0,0,0,0}, a1[8] = {0,0,0,0,0,0,0,0};
            float sacc = 0.f;
            int k = beg;
            for (; k + 6 <= end; k += 6) {
                int e0 = esrc[k],     e1 = esrc[k + 1], e2 = esrc[k + 2];
                int e3 = esrc[k + 3], e4 = esrc[k + 4], e5 = esrc[k + 5];
                uint2 w0 = *(const uint2*)(Hb + (size_t)e0 * 128);
                uint2 w1 = *(const uint2*)(Hb + (size_t)e1 * 128);
                uint2 w2 = *(const uint2*)(Hb + (size_t)e2 * 128);
                uint2 w3 = *(const uint2*)(Hb + (size_t)e3 * 128);
                uint2 w4 = *(const uint2*)(Hb + (size_t)e4 * 128);
                uint2 w5 = *(const uint2*)(Hb + (size_t)e5 * 128);
                float s0 = Hsc[e0], s1 = Hsc[e1], s2 = Hsc[e2];
                float s3 = Hsc[e3], s4 = Hsc[e4], s5 = Hsc[e5];
                acc8(a0, w0, s0); acc8(a1, w1, s1); acc8(a0, w2, s2);
                acc8(a1, w3, s3); acc8(a0, w4, s4); acc8(a1, w5, s5);
                sacc += s0 + s1 + s2 + s3 + s4 + s5;
            }
            for (; k + 2 <= end; k += 2) {
                int e0 = esrc[k], e1 = esrc[k + 1];
                uint2 w0 = *(const uint2*)(Hb + (size_t)e0 * 128);
                uint2 w1 = *(const uint2*)(Hb + (size_t)e1 * 128);
                float s0 = Hsc[e0], s1 = Hsc[e1];
                acc8(a0, w0, s0); acc8(a1, w1, s1);
                sacc += s0 + s1;
            }
            if (k < end) {
                int e0 = esrc[k];
                uint2 w0 = *(const uint2*)(Hb + (size_t)e0 * 128);
                float s0 = Hsc[e0];
                acc8(a0, w0, s0);
                sacc += s0;
            }
            float inv = (end > beg) ? 1.0f / (float)(end - beg) : 0.0f;
            ushort8v mh;
#pragma unroll
            for (int j = 0; j < 8; ++j)
                mh[j] = f2bf((a0[j] + a1[j] - 128.0f * sacc) * inv);
            *(ushort8v*)(&As0[row * PITCH + l16 * 8]) = mh;
        }
    }
    __syncthreads();

    // ---- Phase C: dual GEMM via MFMA (R7-exact) ----
    const int wave = tid >> 6, lane = tid & 63;
    const int rl = lane & 15, quad = lane >> 4;

    f32x4 acc[2][CPW];
#pragma unroll
    for (int c = 0; c < CPW; ++c) {
        float bv = bias[(wave * CPW + c) * 16 + rl];
        acc[0][c] = (f32x4){bv, bv, bv, bv};
        acc[1][c] = acc[0][c];
    }

#pragma unroll
    for (int ks = 0; ks < KS; ++ks) {
        short8 a_ag[2], a_sh[2][2];
#pragma unroll
        for (int rt = 0; rt < 2; ++rt) {
            int off = (rt * 16 + rl) * PITCH + ks * 32 + quad * 8;
            a_ag[rt]    = *(const short8*)(&As0[off]);
            a_sh[rt][0] = *(const short8*)(&As1[off]);
            a_sh[rt][1] = *(const short8*)(&As2[off]);
        }
        short8 b1[CPW][2], b2[CPW][2];
#pragma unroll
        for (int c = 0; c < CPW; ++c) {
            size_t boff = (((wave * CPW + c) * KS + ks) * 64 + lane) * 8;
#pragma unroll
            for (int p = 0; p < 2; ++p) {
                b1[c][p] = *(const short8*)(B1p + p * HALF + boff);
                b2[c][p] = *(const short8*)(B2p + p * HALF + boff);
            }
        }
#pragma unroll
        for (int rt = 0; rt < 2; ++rt)
#pragma unroll
            for (int c = 0; c < CPW; ++c) {
                acc[rt][c] = __builtin_amdgcn_mfma_f32_16x16x32_bf16(a_ag[rt],    b1[c][0], acc[rt][c], 0, 0, 0);
                acc[rt][c] = __builtin_amdgcn_mfma_f32_16x16x32_bf16(a_ag[rt],    b1[c][1], acc[rt][c], 0, 0, 0);
                acc[rt][c] = __builtin_amdgcn_mfma_f32_16x16x32_bf16(a_sh[rt][0], b2[c][0], acc[rt][c], 0, 0, 0);
                acc[rt][c] = __builtin_amdgcn_mfma_f32_16x16x32_bf16(a_sh[rt][0], b2[c][1], acc[rt][c], 0, 0, 0);
                acc[rt][c] = __builtin_amdgcn_mfma_f32_16x16x32_bf16(a_sh[rt][1], b2[c][0], acc[rt][c], 0, 0, 0);
            }
    }

    // ---- apply ReLU once, in-register ----
    if (RELU) {
#pragma unroll
        for (int rt = 0; rt < 2; ++rt)
#pragma unroll
            for (int c = 0; c < CPW; ++c)
#pragma unroll
                for (int r = 0; r < 4; ++r)
                    acc[rt][c][r] = fmaxf(acc[rt][c][r], 0.f);
    }

    float qsc[2][4];
    if constexpr (SPLIT_OUT) {
        float lm[2][4];
#pragma unroll
        for (int rt = 0; rt < 2; ++rt)
#pragma unroll
            for (int r = 0; r < 4; ++r) {
                float m = fabsf(acc[rt][0][r]);
#pragma unroll
                for (int c = 1; c < CPW; ++c) m = fmaxf(m, fabsf(acc[rt][c][r]));
                lm[rt][r] = m;
            }
#pragma unroll
        for (int off = 1; off < 16; off <<= 1)
#pragma unroll
            for (int rt = 0; rt < 2; ++rt)
#pragma unroll
                for (int r = 0; r < 4; ++r)
                    lm[rt][r] = fmaxf(lm[rt][r], __shfl_xor(lm[rt][r], off));
        if (rl == 0) {
#pragma unroll
            for (int rt = 0; rt < 2; ++rt)
#pragma unroll
                for (int r = 0; r < 4; ++r)
                    wmax[rt * 16 + quad * 4 + r][wave] = lm[rt][r];
        }
        __syncthreads();
#pragma unroll
        for (int rt = 0; rt < 2; ++rt)
#pragma unroll
            for (int r = 0; r < 4; ++r) {
                int row = rt * 16 + quad * 4 + r;
                float rm = fmaxf(fmaxf(wmax[row][0], wmax[row][1]),
                                 fmaxf(wmax[row][2], wmax[row][3]));
                qsc[rt][r] = rm > 0.f ? 127.0f / rm : 0.0f;
                if (wave == 0 && rl == 0) {
                    int rr = r0 + row;
                    if (rr < M) outsc[rr] = rm * (1.0f / 127.0f);
                }
            }
    }

    // ---- epilogue: C/D layout col=lane&15, row=quad*4+reg ----
#pragma unroll
    for (int rt = 0; rt < 2; ++rt)
#pragma unroll
        for (int c = 0; c < CPW; ++c) {
            int col = (wave * CPW + c) * 16 + rl;
            int rowb = r0 + rt * 16 + quad * 4;
#pragma unroll
            for (int r = 0; r < 4; ++r) {
                int rr = rowb + r;
                if (rr < M) {
                    float vv = acc[rt][c][r];
                    if (SPLIT_OUT) {
                        unsigned short h, l;
                        split_bf16(vv, h, l);
                        outhi[(size_t)rr * DOUT + col] = h;
                        outlo[(size_t)rr * DOUT + col] = l;
                        outq[(size_t)rr * DOUT + col] = q8(vv, qsc[rt][r]);
                    } else {
                        outf[(size_t)rr * DOUT + col] = vv;
                    }
                }
            }
        }
    __syncthreads();   // LDS reuse safety across grid-stride iterations
}

// ---------------- mega kernel: all 6 phases, 5 device-wide barriers ----------

__global__ __launch_bounds__(256, 4) void mega_kernel(
    const float* __restrict__ Wl0, const float* __restrict__ Wr0,
    const float* __restrict__ Wl1, const float* __restrict__ Wr1,
    const float* __restrict__ Wl2, const float* __restrict__ Wr2,
    unsigned short* __restrict__ packw, const float* __restrict__ x,
    unsigned short* __restrict__ xhi, unsigned short* __restrict__ xlo,
    unsigned char* __restrict__ xq, float* __restrict__ xsc,
    unsigned short* __restrict__ yhi, unsigned short* __restrict__ ylo,
    unsigned char* __restrict__ yq, float* __restrict__ ysc,
    const int* __restrict__ src, const int* __restrict__ dst,
    int* __restrict__ bucketCur, unsigned int* __restrict__ ebuf,
    int* __restrict__ rowbeg, int* __restrict__ rowend,
    unsigned short* __restrict__ esrc,
    const float* __restrict__ b0, const float* __restrict__ b1,
    const float* __restrict__ b2, float* __restrict__ outp,
    int* __restrict__ gbar) {
    __shared__ __align__(16) unsigned char smem[26624];
    const int tid = threadIdx.x;
    const int gsz = gridDim.x;

    // P0: prep (pack W + split/quantize x + zero bucketCur)
    for (int vb = blockIdx.x; vb < 1884; vb += gsz)
        prep_vb(vb, tid, Wl0, Wr0, Wl1, Wr1, Wl2, Wr2, packw, x, xhi, xlo, xq, xsc, bucketCur);
    grid_sync(gbar);
    // P1: partition edges into fixed bucket regions
    for (int vb = blockIdx.x; vb < NPART; vb += gsz)
        partition_vb(vb, tid, smem, src, dst, bucketCur, ebuf, N_EDGES);
    grid_sync(gbar);
    // P2: per-bucket rowbeg/rowend + esrc scatter (consumes ebuf before yhi written)
    for (int vb = blockIdx.x; vb < NBUCK; vb += gsz)
        finefill_vb(vb, tid, smem, ebuf, bucketCur, rowbeg, rowend, esrc, N_NODES);
    grid_sync(gbar);
    // P3: layer 0, x -> y (ReLU)
    for (int vb = blockIdx.x; vb < NTILE; vb += gsz)
        sage_tile<128, true, true>(vb, tid, smem, xq, xsc, xhi, xlo, rowbeg, rowend, esrc,
                                   packw, packw + 32768, b0,
                                   nullptr, yhi, ylo, yq, ysc, N_NODES);
    grid_sync(gbar);
    // P4: layer 1, y -> x (ReLU)
    for (int vb = blockIdx.x; vb < NTILE; vb += gsz)
        sage_tile<128, true, true>(vb, tid, smem, yq, ysc, yhi, ylo, rowbeg, rowend, esrc,
                                   packw + 65536, packw + 98304, b1,
                                   nullptr, xhi, xlo, xq, xsc, N_NODES);
    grid_sync(gbar);
    // P5: layer 2, x -> out (f32, no ReLU, DOUT=64)
    for (int vb = blockIdx.x; vb < NTILE; vb += gsz)
        sage_tile<64, false, false>(vb, tid, smem, xq, xsc, xhi, xlo, rowbeg, rowend, esrc,
                                    packw + 131072, packw + 147456, b2,
                                    outp, nullptr, nullptr, nullptr, nullptr, N_NODES);
}

// ---------------- launch ----------------

extern "C" void kernel_launch(void* const* d_in, const int* in_sizes, int n_in,
                              void* d_out, int out_size, void* d_ws, size_t ws_size,
                              hipStream_t stream) {
    const float* x   = (const float*)d_in[0];
    const int* eidx  = (const int*)d_in[1];
    const int* src   = eidx;             // edge_index[0]
    const int* dst   = eidx + N_EDGES;   // edge_index[1]
    const float* Wl0 = (const float*)d_in[2];
    const float* b0  = (const float*)d_in[3];
    const float* Wr0 = (const float*)d_in[4];
    const float* Wl1 = (const float*)d_in[5];
    const float* b1  = (const float*)d_in[6];
    const float* Wr1 = (const float*)d_in[7];
    const float* Wl2 = (const float*)d_in[8];
    const float* b2  = (const float*)d_in[9];
    const float* Wr2 = (const float*)d_in[10];
    float* outp = (float*)d_out;

    // workspace (~70 MB): ping-pong plane sets + fixed-region CSR scratch
    unsigned short* xhi  = (unsigned short*)d_ws;             // N*128 u16 each
    unsigned short* xlo  = xhi + (size_t)N_NODES * 128;
    unsigned short* yhi  = xlo + (size_t)N_NODES * 128;
    unsigned short* ylo  = yhi + (size_t)N_NODES * 128;
    unsigned int* ebuf = (unsigned int*)yhi;                  // ALIAS: NBUCK*BCAP u32 =
                                                              // 6.4MB, consumed by P2
                                                              // before P3 writes yhi
    unsigned char* xq = (unsigned char*)(ylo + (size_t)N_NODES * 128);  // N*128 u8
    unsigned char* yq = xq + (size_t)N_NODES * 128;
    float* xsc = (float*)(yq + (size_t)N_NODES * 128);        // N f32
    float* ysc = xsc + N_NODES;
    int* rowbeg = (int*)(ysc + N_NODES);                      // N i32
    int* rowend = rowbeg + N_NODES;
    int* bucketCur = rowend + N_NODES;                        // 256 i32
    int* gbar = bucketCur + 256;                              // 16 i32 (2 used)
    unsigned short* esrc = (unsigned short*)(gbar + 16);      // NBUCK*BCAP u16 = 3.2MB
    unsigned short* packw = esrc + NBUCK * BCAP;              // 163840 bf16
    // weight plane offsets inside packw: Wl0p=+0, Wr0p=+32768, Wl1p=+65536,
    // Wr1p=+98304, Wl2p=+131072, Wr2p=+147456 (computed in-kernel)

    hipMemsetAsync(gbar, 0, 2 * sizeof(int), stream);   // barrier state per replay
    mega_kernel<<<GRID_BLOCKS, 256, 0, stream>>>(
        Wl0, Wr0, Wl1, Wr1, Wl2, Wr2, packw, x,
        xhi, xlo, xq, xsc, yhi, ylo, yq, ysc,
        src, dst, bucketCur, ebuf, rowbeg, rowend, esrc,
        b0, b1, b2, outp, gbar);
}

// Round 13
// 228.617 us; speedup vs baseline: 7.2218x; 7.2218x over previous
//
#include <hip/hip_runtime.h>

#define N_NODES 50000
#define N_EDGES 800000
#define NBUCK 196       // dst>>8 -> 0..195
#define NPART 391       // partition blocks (2048 edges each)
#define CELLCAP 36      // max edges per (bucket, partition-block) cell; P(ovf)~1e-10
#define BCAPN (NPART * CELLCAP)   // 14076 slots per bucket region

typedef __attribute__((ext_vector_type(8))) short short8;
typedef __attribute__((ext_vector_type(4))) float f32x4;
typedef __attribute__((ext_vector_type(8))) unsigned short ushort8v;
typedef __attribute__((ext_vector_type(16))) unsigned char uchar16;

// ---------------- helpers ----------------

__device__ inline void split_bf16(float f, unsigned short& hi, unsigned short& lo) {
    union { float f; unsigned u; } a; a.f = f;
    unsigned r = (a.u + 0x7fffu + ((a.u >> 16) & 1u)) >> 16;  // RNE to bf16
    hi = (unsigned short)r;
    union { unsigned u; float f; } b; b.u = r << 16;
    union { float f; unsigned u; } c; c.f = f - b.f;
    unsigned r2 = (c.u + 0x7fffu + ((c.u >> 16) & 1u)) >> 16;
    lo = (unsigned short)r2;
}

__device__ inline unsigned short f2bf(float f) {
    union { float f; unsigned u; } a; a.f = f;
    return (unsigned short)((a.u + 0x7fffu + ((a.u >> 16) & 1u)) >> 16);
}

__device__ inline float bf2f(unsigned short u) {
    union { unsigned u; float f; } a; a.u = (unsigned)u << 16; return a.f;
}

__device__ inline unsigned char q8(float v, float qs) {
    int qi = (int)rintf(v * qs);
    qi = qi > 127 ? 127 : (qi < -127 ? -127 : qi);
    return (unsigned char)(qi + 128);
}

// accumulate 8 biased-u8 values (uint2) scaled by s into a[0..7]
__device__ inline void acc8(float* a, uint2 w, float s) {
#pragma unroll
    for (int j = 0; j < 4; ++j) {
        a[j]     += (float)((w.x >> (8 * j)) & 255u) * s;
        a[j + 4] += (float)((w.y >> (8 * j)) & 255u) * s;
    }
}

// ---------------- prep+partition (merged, R13) -------------------------------
// R13: prep (pack W, split/quantize x) and edge-partition are mutually
// independent, so they share ONE kernel (R9/R10 lesson: ~8us/dispatch).
// Partition is deterministic & atomic-free: block pb writes its bucket-b run
// into fixed cell ebuf[b*BCAPN + pb*CELLCAP] and stores the count to
// cellcnt[b*NPART+pb] (plain stores, no init needed, no bucketCur).

__global__ __launch_bounds__(256) void prep_part_kernel(
    const float* __restrict__ W0, const float* __restrict__ W1,
    const float* __restrict__ W2, const float* __restrict__ W3,
    const float* __restrict__ W4, const float* __restrict__ W5,
    unsigned short* __restrict__ wout,
    const float* __restrict__ x, unsigned short* __restrict__ xhi,
    unsigned short* __restrict__ xlo,
    unsigned char* __restrict__ xq, float* __restrict__ xsc,
    const int* __restrict__ src, const int* __restrict__ dst,
    unsigned int* __restrict__ ebuf, int* __restrict__ cellcnt) {
    __shared__ int hist[NBUCK], binoff[NBUCK], bincur[NBUCK];
    __shared__ int scanbuf[256];
    __shared__ unsigned int sortbuf[2048];
    const int vb = blockIdx.x, tid = threadIdx.x;
    if (vb < 320) {
        int t = vb * 256 + tid;  // 0..81919
        const float* W; int D, local, half; size_t base;
        if (t < 65536) {
            int mat = t >> 14; local = t & 16383; D = 128; half = 16384;
            base = (size_t)mat * 32768;
            W = mat == 0 ? W0 : mat == 1 ? W1 : mat == 2 ? W2 : W3;
        } else {
            int m = (t - 65536) >> 13; local = (t - 65536) & 8191; D = 64; half = 8192;
            base = 131072 + (size_t)m * 16384;
            W = m == 0 ? W4 : W5;
        }
        int j = local & 7, lane = (local >> 3) & 63, ks = (local >> 9) & 3, ct = local >> 11;
        int k = ks * 32 + ((lane >> 4) << 3) + j;
        int n = (ct << 4) + (lane & 15);
        unsigned short hi, lo;
        split_bf16(W[k * D + n], hi, lo);
        wout[base + local] = hi;
        wout[base + half + local] = lo;
    } else if (vb < 1883) {
        int t = (vb - 320) * 256 + tid;          // one 16-float chunk/thread
        if (t >= N_NODES * 8) return;            // 50000*128/16 = 400000
        const float* p = x + (size_t)t * 16;
        float4 v0 = *(const float4*)(p);
        float4 v1 = *(const float4*)(p + 4);
        float4 v2 = *(const float4*)(p + 8);
        float4 v3 = *(const float4*)(p + 12);
        float vv[16] = {v0.x, v0.y, v0.z, v0.w, v1.x, v1.y, v1.z, v1.w,
                        v2.x, v2.y, v2.z, v2.w, v3.x, v3.y, v3.z, v3.w};
        // rowmax over 128 floats: 8 consecutive threads share a row (aligned)
        float m = 0.f;
#pragma unroll
        for (int j = 0; j < 16; ++j) m = fmaxf(m, fabsf(vv[j]));
        m = fmaxf(m, __shfl_xor(m, 1));
        m = fmaxf(m, __shfl_xor(m, 2));
        m = fmaxf(m, __shfl_xor(m, 4));
        float qs = m > 0.f ? 127.0f / m : 0.0f;
        uchar16 qv;
        ushort8v h0, l0, h1, l1;
#pragma unroll
        for (int j = 0; j < 16; ++j) {
            unsigned short a, b;
            split_bf16(vv[j], a, b);
            if (j < 8) { h0[j] = a; l0[j] = b; } else { h1[j - 8] = a; l1[j - 8] = b; }
            qv[j] = q8(vv[j], qs);
        }
        *(ushort8v*)(xhi + (size_t)t * 16) = h0;
        *(ushort8v*)(xhi + (size_t)t * 16 + 8) = h1;
        *(ushort8v*)(xlo + (size_t)t * 16) = l0;
        *(ushort8v*)(xlo + (size_t)t * 16 + 8) = l1;
        *(uchar16*)(xq + (size_t)t * 16) = qv;
        if ((t & 7) == 0) xsc[t >> 3] = m * (1.0f / 127.0f);
    } else {
        const int pb = vb - 1883;      // 0..390
        const int base = pb * 2048;
        if (tid < NBUCK) hist[tid] = 0;
        __syncthreads();
        int myb[8]; unsigned int myp[8];
#pragma unroll
        for (int i = 0; i < 8; ++i) {
            int e = base + i * 256 + tid;
            if (e < N_EDGES) {
                int d = dst[e], s = src[e];
                myb[i] = d >> 8;
                myp[i] = ((unsigned)d << 16) | (unsigned)s;
                atomicAdd(&hist[myb[i]], 1);
            } else myb[i] = -1;
        }
        __syncthreads();
        int v = (tid < NBUCK) ? hist[tid] : 0;
        scanbuf[tid] = v;
        __syncthreads();
        for (int off = 1; off < 256; off <<= 1) {
            int t = (tid >= off) ? scanbuf[tid - off] : 0;
            __syncthreads();
            scanbuf[tid] += t;
            __syncthreads();
        }
        if (tid < NBUCK) {
            binoff[tid] = scanbuf[tid] - v;
            bincur[tid] = 0;
        }
        __syncthreads();
#pragma unroll
        for (int i = 0; i < 8; ++i) {
            if (myb[i] >= 0) {
                int r = atomicAdd(&bincur[myb[i]], 1);
                sortbuf[binoff[myb[i]] + r] = myp[i];
            }
        }
        __syncthreads();
        int nloc = N_EDGES - base; if (nloc > 2048) nloc = 2048;
#pragma unroll
        for (int i = 0; i < 8; ++i) {
            int idx = i * 256 + tid;
            if (idx < nloc) {
                unsigned int p = sortbuf[idx];
                int b = p >> 24;   // dst>>8
                int off = idx - binoff[b];
                if (off < CELLCAP)
                    ebuf[(size_t)b * BCAPN + pb * CELLCAP + off] = p;
            }
        }
        if (tid < NBUCK)
            cellcnt[tid * NPART + pb] = (hist[tid] < CELLCAP) ? hist[tid] : CELLCAP;
    }
}

// ---------------- fine fill: per bucket -> rowbeg/rowend + esrc --------------
// Walks the NPART fixed cells of its bucket (<=CELLCAP edges each) instead of
// a contiguous run; LDS histogram/scan/scatter unchanged from R10/R11.

__global__ __launch_bounds__(256) void fine_fill_kernel(
    const unsigned int* __restrict__ ebuf, const int* __restrict__ cellcnt,
    int* __restrict__ rowbeg, int* __restrict__ rowend,
    unsigned short* __restrict__ esrc, int n) {
    __shared__ int cnt[256], scanbuf[256], cur[256];
    const int b = blockIdx.x, tid = threadIdx.x;
    const int nbase = b << 8;
    cnt[tid] = 0;
    __syncthreads();
    const size_t lo = (size_t)b * BCAPN;
    for (int i = tid; i < NPART; i += 256) {
        int c = cellcnt[b * NPART + i];
        const unsigned int* cell = ebuf + lo + i * CELLCAP;
        for (int k = 0; k < c; ++k)
            atomicAdd(&cnt[(cell[k] >> 16) & 255], 1);
    }
    __syncthreads();
    int v = cnt[tid];
    scanbuf[tid] = v;
    __syncthreads();
    for (int off = 1; off < 256; off <<= 1) {
        int t = (tid >= off) ? scanbuf[tid - off] : 0;
        __syncthreads();
        scanbuf[tid] += t;
        __syncthreads();
    }
    int start = (int)lo + scanbuf[tid] - v;   // exclusive
    if (nbase + tid < n) { rowbeg[nbase + tid] = start; rowend[nbase + tid] = start + v; }
    cur[tid] = start;
    __syncthreads();
    for (int i = tid; i < NPART; i += 256) {
        int c = cellcnt[b * NPART + i];
        const unsigned int* cell = ebuf + lo + i * CELLCAP;
        for (int k = 0; k < c; ++k) {
            unsigned int p = cell[k];
            int pos = atomicAdd(&cur[(p >> 16) & 255], 1);
            esrc[pos] = (unsigned short)(p & 0xFFFFu);
        }
    }
}

// ---------------- fused SAGE layer: 512 threads (R11-verbatim) ---------------

template <int DOUT, bool RELU, bool SPLIT_OUT>
__global__ __launch_bounds__(512, 6) void sage_layer(
    const unsigned char* __restrict__ Hq, const float* __restrict__ Hsc,
    const unsigned short* __restrict__ Hhi, const unsigned short* __restrict__ Hlo,
    const int* __restrict__ rowbeg, const int* __restrict__ rowend,
    const unsigned short* __restrict__ esrc,
    const unsigned short* __restrict__ B1p, const unsigned short* __restrict__ B2p,
    const float* __restrict__ bias, float* __restrict__ outf,
    unsigned short* __restrict__ outhi, unsigned short* __restrict__ outlo,
    unsigned char* __restrict__ outq, float* __restrict__ outsc, int M) {
    constexpr int K = 128, BM = 32, KS = 4, CT = DOUT / 16;
    constexpr int PITCH = K + 8;
    constexpr int HALF = CT * KS * 512;
    constexpr bool SPLITRT = (CT == 4);     // 8 waves > col tiles -> split rt
    constexpr int RTN = SPLITRT ? 1 : 2;    // row-tiles handled per wave
    __shared__ unsigned short As[3][BM * PITCH];  // [agg-hi, self-hi, self-lo]
    __shared__ float wmax[BM][8];

    const int tid = threadIdx.x;
    const int r0 = blockIdx.x * BM;

    // ---- Phase A: stage self hi/lo rows (coalesced; 1 chunk/thread/plane) ----
    const unsigned short* __restrict__ srcs[2] = {Hhi, Hlo};
#pragma unroll
    for (int s = 0; s < 2; ++s) {
        int row = tid >> 4;                  // 0..31
        int c8 = (tid & 15) * 8;
        int grow = r0 + row; if (grow >= M) grow = M - 1;
        *(ushort8v*)(&As[s + 1][row * PITCH + c8]) =
            *(const ushort8v*)(srcs[s] + (size_t)grow * K + c8);
    }

    // ---- Phase B: int8 gather-mean into As[0] (R7 loop body, 1 row/group) ---
    {
        const int g16 = tid >> 4, l16 = tid & 15;   // g16: 0..31 = row
        const unsigned char* __restrict__ Hb = Hq + l16 * 8;
        int node = r0 + g16; if (node >= M) node = M - 1;  // pad: harmless dup
        int beg = rowbeg[node], end = rowend[node];
        float a0[8] = {0,0,0,0,0,0,0,0}, a1[8] = {0,0,0,0,0,0,0,0};
        float sacc = 0.f;
        int k = beg;
        for (; k + 6 <= end; k += 6) {
            int e0 = esrc[k],     e1 = esrc[k + 1], e2 = esrc[k + 2];
            int e3 = esrc[k + 3], e4 = esrc[k + 4], e5 = esrc[k + 5];
            uint2 w0 = *(const uint2*)(Hb + (size_t)e0 * 128);
            uint2 w1 = *(const uint2*)(Hb + (size_t)e1 * 128);
            uint2 w2 = *(const uint2*)(Hb + (size_t)e2 * 128);
            uint2 w3 = *(const uint2*)(Hb + (size_t)e3 * 128);
            uint2 w4 = *(const uint2*)(Hb + (size_t)e4 * 128);
            uint2 w5 = *(const uint2*)(Hb + (size_t)e5 * 128);
            float s0 = Hsc[e0], s1 = Hsc[e1], s2 = Hsc[e2];
            float s3 = Hsc[e3], s4 = Hsc[e4], s5 = Hsc[e5];
            acc8(a0, w0, s0); acc8(a1, w1, s1); acc8(a0, w2, s2);
            acc8(a1, w3, s3); acc8(a0, w4, s4); acc8(a1, w5, s5);
            sacc += s0 + s1 + s2 + s3 + s4 + s5;
        }
        for (; k + 2 <= end; k += 2) {
            int e0 = esrc[k], e1 = esrc[k + 1];
            uint2 w0 = *(const uint2*)(Hb + (size_t)e0 * 128);
            uint2 w1 = *(const uint2*)(Hb + (size_t)e1 * 128);
            float s0 = Hsc[e0], s1 = Hsc[e1];
            acc8(a0, w0, s0); acc8(a1, w1, s1);
            sacc += s0 + s1;
        }
        if (k < end) {
            int e0 = esrc[k];
            uint2 w0 = *(const uint2*)(Hb + (size_t)e0 * 128);
            float s0 = Hsc[e0];
            acc8(a0, w0, s0);
            sacc += s0;
        }
        float inv = (end > beg) ? 1.0f / (float)(end - beg) : 0.0f;
        ushort8v mh;
#pragma unroll
        for (int j = 0; j < 8; ++j)
            mh[j] = f2bf((a0[j] + a1[j] - 128.0f * sacc) * inv);
        *(ushort8v*)(&As[0][g16 * PITCH + l16 * 8]) = mh;
    }
    __syncthreads();

    // ---- Phase C: dual GEMM via MFMA over 8 waves ----
    const int wave = tid >> 6, lane = tid & 63;
    const int rl = lane & 15, quad = lane >> 4;
    const int ct = SPLITRT ? (wave & 3) : wave;   // column tile
    const int rt0 = SPLITRT ? (wave >> 2) : 0;    // first row tile

    f32x4 acc[RTN];
    {
        float bv = bias[ct * 16 + rl];
#pragma unroll
        for (int ri = 0; ri < RTN; ++ri) acc[ri] = (f32x4){bv, bv, bv, bv};
    }

#pragma unroll
    for (int ks = 0; ks < KS; ++ks) {
        short8 a_ag[RTN], a_sh[RTN][2];
#pragma unroll
        for (int ri = 0; ri < RTN; ++ri) {
            int rt = rt0 + ri;
            int off = (rt * 16 + rl) * PITCH + ks * 32 + quad * 8;
            a_ag[ri]    = *(const short8*)(&As[0][off]);
            a_sh[ri][0] = *(const short8*)(&As[1][off]);
            a_sh[ri][1] = *(const short8*)(&As[2][off]);
        }
        size_t boff = (((size_t)ct * KS + ks) * 64 + lane) * 8;
        short8 b1h = *(const short8*)(B1p + boff);
        short8 b1l = *(const short8*)(B1p + HALF + boff);
        short8 b2h = *(const short8*)(B2p + boff);
        short8 b2l = *(const short8*)(B2p + HALF + boff);
#pragma unroll
        for (int ri = 0; ri < RTN; ++ri) {
            acc[ri] = __builtin_amdgcn_mfma_f32_16x16x32_bf16(a_ag[ri],    b1h, acc[ri], 0, 0, 0);
            acc[ri] = __builtin_amdgcn_mfma_f32_16x16x32_bf16(a_ag[ri],    b1l, acc[ri], 0, 0, 0);
            acc[ri] = __builtin_amdgcn_mfma_f32_16x16x32_bf16(a_sh[ri][0], b2h, acc[ri], 0, 0, 0);
            acc[ri] = __builtin_amdgcn_mfma_f32_16x16x32_bf16(a_sh[ri][0], b2l, acc[ri], 0, 0, 0);
            acc[ri] = __builtin_amdgcn_mfma_f32_16x16x32_bf16(a_sh[ri][1], b2h, acc[ri], 0, 0, 0);
        }
    }

    // ---- apply ReLU once, in-register ----
    if (RELU) {
#pragma unroll
        for (int ri = 0; ri < RTN; ++ri)
#pragma unroll
            for (int r = 0; r < 4; ++r)
                acc[ri][r] = fmaxf(acc[ri][r], 0.f);
    }

    float qsc[RTN][4];
    if constexpr (SPLIT_OUT) {
        float lm[RTN][4];
#pragma unroll
        for (int ri = 0; ri < RTN; ++ri)
#pragma unroll
            for (int r = 0; r < 4; ++r) lm[ri][r] = fabsf(acc[ri][r]);
#pragma unroll
        for (int off = 1; off < 16; off <<= 1)
#pragma unroll
            for (int ri = 0; ri < RTN; ++ri)
#pragma unroll
                for (int r = 0; r < 4; ++r)
                    lm[ri][r] = fmaxf(lm[ri][r], __shfl_xor(lm[ri][r], off));
        if (rl == 0) {
#pragma unroll
            for (int ri = 0; ri < RTN; ++ri)
#pragma unroll
                for (int r = 0; r < 4; ++r)
                    wmax[(rt0 + ri) * 16 + quad * 4 + r][wave] = lm[ri][r];
        }
        __syncthreads();
#pragma unroll
        for (int ri = 0; ri < RTN; ++ri)
#pragma unroll
            for (int r = 0; r < 4; ++r) {
                int row = (rt0 + ri) * 16 + quad * 4 + r;
                float rm = fmaxf(fmaxf(fmaxf(wmax[row][0], wmax[row][1]),
                                       fmaxf(wmax[row][2], wmax[row][3])),
                                 fmaxf(fmaxf(wmax[row][4], wmax[row][5]),
                                       fmaxf(wmax[row][6], wmax[row][7])));
                qsc[ri][r] = rm > 0.f ? 127.0f / rm : 0.0f;
                if (wave == 0 && rl == 0) {
                    int rr = r0 + row;
                    if (rr < M) outsc[rr] = rm * (1.0f / 127.0f);
                }
            }
    }

    // ---- epilogue: C/D layout col=lane&15, row=quad*4+reg ----
#pragma unroll
    for (int ri = 0; ri < RTN; ++ri) {
        int rt = rt0 + ri;
        int col = ct * 16 + rl;
        int rowb = r0 + rt * 16 + quad * 4;
#pragma unroll
        for (int r = 0; r < 4; ++r) {
            int rr = rowb + r;
            if (rr < M) {
                float vv = acc[ri][r];
                if (SPLIT_OUT) {
                    unsigned short h, l;
                    split_bf16(vv, h, l);
                    outhi[(size_t)rr * DOUT + col] = h;
                    outlo[(size_t)rr * DOUT + col] = l;
                    outq[(size_t)rr * DOUT + col] = q8(vv, qsc[ri][r]);
                } else {
                    outf[(size_t)rr * DOUT + col] = vv;
                }
            }
        }
    }
}

// ---------------- launch ----------------

extern "C" void kernel_launch(void* const* d_in, const int* in_sizes, int n_in,
                              void* d_out, int out_size, void* d_ws, size_t ws_size,
                              hipStream_t stream) {
    const float* x   = (const float*)d_in[0];
    const int* eidx  = (const int*)d_in[1];
    const int* src   = eidx;             // edge_index[0]
    const int* dst   = eidx + N_EDGES;   // edge_index[1]
    const float* Wl0 = (const float*)d_in[2];
    const float* b0  = (const float*)d_in[3];
    const float* Wr0 = (const float*)d_in[4];
    const float* Wl1 = (const float*)d_in[5];
    const float* b1  = (const float*)d_in[6];
    const float* Wr1 = (const float*)d_in[7];
    const float* Wl2 = (const float*)d_in[8];
    const float* b2  = (const float*)d_in[9];
    const float* Wr2 = (const float*)d_in[10];
    float* outp = (float*)d_out;

    // workspace (~75 MB): ping-pong plane sets + fixed-cell CSR scratch
    unsigned short* xhi  = (unsigned short*)d_ws;             // N*128 u16 each
    unsigned short* xlo  = xhi + (size_t)N_NODES * 128;
    unsigned short* yhi  = xlo + (size_t)N_NODES * 128;
    unsigned short* ylo  = yhi + (size_t)N_NODES * 128;
    unsigned int* ebuf = (unsigned int*)yhi;                  // ALIAS: NBUCK*BCAPN u32 =
                                                              // 11.0MB <= 12.8MB plane;
                                                              // consumed by fine_fill
                                                              // before layer0 writes yhi
    unsigned char* xq = (unsigned char*)(ylo + (size_t)N_NODES * 128);  // N*128 u8
    unsigned char* yq = xq + (size_t)N_NODES * 128;
    float* xsc = (float*)(yq + (size_t)N_NODES * 128);        // N f32
    float* ysc = xsc + N_NODES;
    int* rowbeg = (int*)(ysc + N_NODES);                      // N i32
    int* rowend = rowbeg + N_NODES;
    int* cellcnt = rowend + N_NODES;                          // NBUCK*NPART i32 = 306KB
    unsigned short* esrc = (unsigned short*)(cellcnt + NBUCK * NPART); // NBUCK*BCAPN u16 = 5.5MB
    unsigned short* packw = esrc + (size_t)NBUCK * BCAPN;     // 163840 bf16
    unsigned short* Wl0p = packw;
    unsigned short* Wr0p = packw + 32768;
    unsigned short* Wl1p = packw + 65536;
    unsigned short* Wr1p = packw + 98304;
    unsigned short* Wl2p = packw + 131072;
    unsigned short* Wr2p = packw + 147456;

    // --- prep + partition (merged: independent work, one dispatch) ---
    prep_part_kernel<<<1883 + NPART, 256, 0, stream>>>(
        Wl0, Wr0, Wl1, Wr1, Wl2, Wr2, packw, x, xhi, xlo, xq, xsc,
        src, dst, ebuf, cellcnt);
    // --- per-bucket: rowbeg/rowend + esrc scatter ---
    fine_fill_kernel<<<NBUCK, 256, 0, stream>>>(ebuf, cellcnt, rowbeg, rowend, esrc, N_NODES);

    const int gemmGrid = (N_NODES + 31) / 32;   // 1563

    // layer 0: x-planes -> y-planes (ReLU)
    sage_layer<128, true, true><<<gemmGrid, 512, 0, stream>>>(
        xq, xsc, xhi, xlo, rowbeg, rowend, esrc, Wl0p, Wr0p, b0,
        nullptr, yhi, ylo, yq, ysc, N_NODES);
    // layer 1: y-planes -> x-planes (ReLU)
    sage_layer<128, true, true><<<gemmGrid, 512, 0, stream>>>(
        yq, ysc, yhi, ylo, rowbeg, rowend, esrc, Wl1p, Wr1p, b1,
        nullptr, xhi, xlo, xq, xsc, N_NODES);
    // layer 2: x-planes -> out (f32, no ReLU, DOUT=64)
    sage_layer<64, false, false><<<gemmGrid, 512, 0, stream>>>(
        xq, xsc, xhi, xlo, rowbeg, rowend, esrc, Wl2p, Wr2p, b2,
        outp, nullptr, nullptr, nullptr, nullptr, N_NODES);
}

// Round 14
// 220.533 us; speedup vs baseline: 7.4866x; 1.0367x over previous
//
#include <hip/hip_runtime.h>

#define N_NODES 50000
#define N_EDGES 800000
#define NBUCK 196       // dst>>8 -> 0..195
#define NPART 391       // partition blocks (2048 edges each)
#define CELLCAP 36      // max edges per (bucket, partition-block) cell; P(ovf)~1e-10
#define BCAPN (NPART * CELLCAP)   // 14076 slots per bucket region

typedef __attribute__((ext_vector_type(8))) short short8;
typedef __attribute__((ext_vector_type(4))) float f32x4;
typedef __attribute__((ext_vector_type(8))) unsigned short ushort8v;
typedef __attribute__((ext_vector_type(16))) unsigned char uchar16;

// ---------------- helpers ----------------

__device__ inline void split_bf16(float f, unsigned short& hi, unsigned short& lo) {
    union { float f; unsigned u; } a; a.f = f;
    unsigned r = (a.u + 0x7fffu + ((a.u >> 16) & 1u)) >> 16;  // RNE to bf16
    hi = (unsigned short)r;
    union { unsigned u; float f; } b; b.u = r << 16;
    union { float f; unsigned u; } c; c.f = f - b.f;
    unsigned r2 = (c.u + 0x7fffu + ((c.u >> 16) & 1u)) >> 16;
    lo = (unsigned short)r2;
}

__device__ inline unsigned short f2bf(float f) {
    union { float f; unsigned u; } a; a.f = f;
    return (unsigned short)((a.u + 0x7fffu + ((a.u >> 16) & 1u)) >> 16);
}

__device__ inline float bf2f(unsigned short u) {
    union { unsigned u; float f; } a; a.u = (unsigned)u << 16; return a.f;
}

__device__ inline unsigned char q8(float v, float qs) {
    int qi = (int)rintf(v * qs);
    qi = qi > 127 ? 127 : (qi < -127 ? -127 : qi);
    return (unsigned char)(qi + 128);
}

// accumulate 8 biased-u8 values (uint2) scaled by s into a[0..7]
__device__ inline void acc8(float* a, uint2 w, float s) {
#pragma unroll
    for (int j = 0; j < 4; ++j) {
        a[j]     += (float)((w.x >> (8 * j)) & 255u) * s;
        a[j + 4] += (float)((w.y >> (8 * j)) & 255u) * s;
    }
}

// ---------------- prep+partition (merged; R14: no hi/lo plane writes) --------
// R14: hidden state lives as ONE f32 plane (split to bf16 hi/lo IN-REGISTER at
// Phase A of the layer -> bit-identical MFMA inputs). prep's x-phase now only
// quantizes (writes xq/xsc, 6.6MB vs R13's 32MB). Partition: deterministic,
// atomic-free fixed cells (R13).

__global__ __launch_bounds__(256) void prep_part_kernel(
    const float* __restrict__ W0, const float* __restrict__ W1,
    const float* __restrict__ W2, const float* __restrict__ W3,
    const float* __restrict__ W4, const float* __restrict__ W5,
    unsigned short* __restrict__ wout,
    const float* __restrict__ x,
    unsigned char* __restrict__ xq, float* __restrict__ xsc,
    const int* __restrict__ src, const int* __restrict__ dst,
    unsigned int* __restrict__ ebuf, int* __restrict__ cellcnt) {
    __shared__ int hist[NBUCK], binoff[NBUCK], bincur[NBUCK];
    __shared__ int scanbuf[256];
    __shared__ unsigned int sortbuf[2048];
    const int vb = blockIdx.x, tid = threadIdx.x;
    if (vb < 320) {
        int t = vb * 256 + tid;  // 0..81919
        const float* W; int D, local, half; size_t base;
        if (t < 65536) {
            int mat = t >> 14; local = t & 16383; D = 128; half = 16384;
            base = (size_t)mat * 32768;
            W = mat == 0 ? W0 : mat == 1 ? W1 : mat == 2 ? W2 : W3;
        } else {
            int m = (t - 65536) >> 13; local = (t - 65536) & 8191; D = 64; half = 8192;
            base = 131072 + (size_t)m * 16384;
            W = m == 0 ? W4 : W5;
        }
        int j = local & 7, lane = (local >> 3) & 63, ks = (local >> 9) & 3, ct = local >> 11;
        int k = ks * 32 + ((lane >> 4) << 3) + j;
        int n = (ct << 4) + (lane & 15);
        unsigned short hi, lo;
        split_bf16(W[k * D + n], hi, lo);
        wout[base + local] = hi;
        wout[base + half + local] = lo;
    } else if (vb < 1883) {
        int t = (vb - 320) * 256 + tid;          // one 16-float chunk/thread
        if (t >= N_NODES * 8) return;            // 50000*128/16 = 400000
        const float* p = x + (size_t)t * 16;
        float4 v0 = *(const float4*)(p);
        float4 v1 = *(const float4*)(p + 4);
        float4 v2 = *(const float4*)(p + 8);
        float4 v3 = *(const float4*)(p + 12);
        float vv[16] = {v0.x, v0.y, v0.z, v0.w, v1.x, v1.y, v1.z, v1.w,
                        v2.x, v2.y, v2.z, v2.w, v3.x, v3.y, v3.z, v3.w};
        // rowmax over 128 floats: 8 consecutive threads share a row (aligned)
        float m = 0.f;
#pragma unroll
        for (int j = 0; j < 16; ++j) m = fmaxf(m, fabsf(vv[j]));
        m = fmaxf(m, __shfl_xor(m, 1));
        m = fmaxf(m, __shfl_xor(m, 2));
        m = fmaxf(m, __shfl_xor(m, 4));
        float qs = m > 0.f ? 127.0f / m : 0.0f;
        uchar16 qv;
#pragma unroll
        for (int j = 0; j < 16; ++j) qv[j] = q8(vv[j], qs);
        *(uchar16*)(xq + (size_t)t * 16) = qv;
        if ((t & 7) == 0) xsc[t >> 3] = m * (1.0f / 127.0f);
    } else {
        const int pb = vb - 1883;      // 0..390
        const int base = pb * 2048;
        if (tid < NBUCK) hist[tid] = 0;
        __syncthreads();
        int myb[8]; unsigned int myp[8];
#pragma unroll
        for (int i = 0; i < 8; ++i) {
            int e = base + i * 256 + tid;
            if (e < N_EDGES) {
                int d = dst[e], s = src[e];
                myb[i] = d >> 8;
                myp[i] = ((unsigned)d << 16) | (unsigned)s;
                atomicAdd(&hist[myb[i]], 1);
            } else myb[i] = -1;
        }
        __syncthreads();
        int v = (tid < NBUCK) ? hist[tid] : 0;
        scanbuf[tid] = v;
        __syncthreads();
        for (int off = 1; off < 256; off <<= 1) {
            int t = (tid >= off) ? scanbuf[tid - off] : 0;
            __syncthreads();
            scanbuf[tid] += t;
            __syncthreads();
        }
        if (tid < NBUCK) {
            binoff[tid] = scanbuf[tid] - v;
            bincur[tid] = 0;
        }
        __syncthreads();
#pragma unroll
        for (int i = 0; i < 8; ++i) {
            if (myb[i] >= 0) {
                int r = atomicAdd(&bincur[myb[i]], 1);
                sortbuf[binoff[myb[i]] + r] = myp[i];
            }
        }
        __syncthreads();
        int nloc = N_EDGES - base; if (nloc > 2048) nloc = 2048;
#pragma unroll
        for (int i = 0; i < 8; ++i) {
            int idx = i * 256 + tid;
            if (idx < nloc) {
                unsigned int p = sortbuf[idx];
                int b = p >> 24;   // dst>>8
                int off = idx - binoff[b];
                if (off < CELLCAP)
                    ebuf[(size_t)b * BCAPN + pb * CELLCAP + off] = p;
            }
        }
        if (tid < NBUCK)
            cellcnt[tid * NPART + pb] = (hist[tid] < CELLCAP) ? hist[tid] : CELLCAP;
    }
}

// ---------------- fine fill: per bucket -> rowbeg/rowend + esrc (R13-frozen) --

__global__ __launch_bounds__(256) void fine_fill_kernel(
    const unsigned int* __restrict__ ebuf, const int* __restrict__ cellcnt,
    int* __restrict__ rowbeg, int* __restrict__ rowend,
    unsigned short* __restrict__ esrc, int n) {
    __shared__ int cnt[256], scanbuf[256], cur[256];
    const int b = blockIdx.x, tid = threadIdx.x;
    const int nbase = b << 8;
    cnt[tid] = 0;
    __syncthreads();
    const size_t lo = (size_t)b * BCAPN;
    for (int i = tid; i < NPART; i += 256) {
        int c = cellcnt[b * NPART + i];
        const unsigned int* cell = ebuf + lo + i * CELLCAP;
        for (int k = 0; k < c; ++k)
            atomicAdd(&cnt[(cell[k] >> 16) & 255], 1);
    }
    __syncthreads();
    int v = cnt[tid];
    scanbuf[tid] = v;
    __syncthreads();
    for (int off = 1; off < 256; off <<= 1) {
        int t = (tid >= off) ? scanbuf[tid - off] : 0;
        __syncthreads();
        scanbuf[tid] += t;
        __syncthreads();
    }
    int start = (int)lo + scanbuf[tid] - v;   // exclusive
    if (nbase + tid < n) { rowbeg[nbase + tid] = start; rowend[nbase + tid] = start + v; }
    cur[tid] = start;
    __syncthreads();
    for (int i = tid; i < NPART; i += 256) {
        int c = cellcnt[b * NPART + i];
        const unsigned int* cell = ebuf + lo + i * CELLCAP;
        for (int k = 0; k < c; ++k) {
            unsigned int p = cell[k];
            int pos = atomicAdd(&cur[(p >> 16) & 255], 1);
            esrc[pos] = (unsigned short)(p & 0xFFFFu);
        }
    }
}

// ---------------- fused SAGE layer: 512 threads, f32 self plane (R14) --------
// R13-verbatim except: self input is ONE f32 plane (Hf); Phase A splits to
// bf16 hi/lo IN-REGISTER (same split_bf16 -> bit-identical MFMA inputs);
// epilogue writes f32 (+int8/scale when QOUT).

template <int DOUT, bool RELU, bool QOUT>
__global__ __launch_bounds__(512, 6) void sage_layer(
    const unsigned char* __restrict__ Hq, const float* __restrict__ Hsc,
    const float* __restrict__ Hf,
    const int* __restrict__ rowbeg, const int* __restrict__ rowend,
    const unsigned short* __restrict__ esrc,
    const unsigned short* __restrict__ B1p, const unsigned short* __restrict__ B2p,
    const float* __restrict__ bias, float* __restrict__ outf,
    unsigned char* __restrict__ outq, float* __restrict__ outsc, int M) {
    constexpr int K = 128, BM = 32, KS = 4, CT = DOUT / 16;
    constexpr int PITCH = K + 8;
    constexpr int HALF = CT * KS * 512;
    constexpr bool SPLITRT = (CT == 4);     // 8 waves > col tiles -> split rt
    constexpr int RTN = SPLITRT ? 1 : 2;    // row-tiles handled per wave
    __shared__ unsigned short As[3][BM * PITCH];  // [agg-hi, self-hi, self-lo]
    __shared__ float wmax[BM][8];

    const int tid = threadIdx.x;
    const int r0 = blockIdx.x * BM;

    // ---- Phase A: read f32 self row, split to hi/lo in-register, stage LDS ---
    {
        int row = tid >> 4;                  // 0..31
        int c8 = (tid & 15) * 8;
        int grow = r0 + row; if (grow >= M) grow = M - 1;
        const float* sp = Hf + (size_t)grow * K + c8;
        float4 v0 = *(const float4*)(sp);
        float4 v1 = *(const float4*)(sp + 4);
        float vv[8] = {v0.x, v0.y, v0.z, v0.w, v1.x, v1.y, v1.z, v1.w};
        ushort8v h, l;
#pragma unroll
        for (int j = 0; j < 8; ++j) {
            unsigned short a, b;
            split_bf16(vv[j], a, b);
            h[j] = a; l[j] = b;
        }
        *(ushort8v*)(&As[1][row * PITCH + c8]) = h;
        *(ushort8v*)(&As[2][row * PITCH + c8]) = l;
    }

    // ---- Phase B: int8 gather-mean into As[0] (R7 loop body, 1 row/group) ---
    {
        const int g16 = tid >> 4, l16 = tid & 15;   // g16: 0..31 = row
        const unsigned char* __restrict__ Hb = Hq + l16 * 8;
        int node = r0 + g16; if (node >= M) node = M - 1;  // pad: harmless dup
        int beg = rowbeg[node], end = rowend[node];
        float a0[8] = {0,0,0,0,0,0,0,0}, a1[8] = {0,0,0,0,0,0,0,0};
        float sacc = 0.f;
        int k = beg;
        for (; k + 6 <= end; k += 6) {
            int e0 = esrc[k],     e1 = esrc[k + 1], e2 = esrc[k + 2];
            int e3 = esrc[k + 3], e4 = esrc[k + 4], e5 = esrc[k + 5];
            uint2 w0 = *(const uint2*)(Hb + (size_t)e0 * 128);
            uint2 w1 = *(const uint2*)(Hb + (size_t)e1 * 128);
            uint2 w2 = *(const uint2*)(Hb + (size_t)e2 * 128);
            uint2 w3 = *(const uint2*)(Hb + (size_t)e3 * 128);
            uint2 w4 = *(const uint2*)(Hb + (size_t)e4 * 128);
            uint2 w5 = *(const uint2*)(Hb + (size_t)e5 * 128);
            float s0 = Hsc[e0], s1 = Hsc[e1], s2 = Hsc[e2];
            float s3 = Hsc[e3], s4 = Hsc[e4], s5 = Hsc[e5];
            acc8(a0, w0, s0); acc8(a1, w1, s1); acc8(a0, w2, s2);
            acc8(a1, w3, s3); acc8(a0, w4, s4); acc8(a1, w5, s5);
            sacc += s0 + s1 + s2 + s3 + s4 + s5;
        }
        for (; k + 2 <= end; k += 2) {
            int e0 = esrc[k], e1 = esrc[k + 1];
            uint2 w0 = *(const uint2*)(Hb + (size_t)e0 * 128);
            uint2 w1 = *(const uint2*)(Hb + (size_t)e1 * 128);
            float s0 = Hsc[e0], s1 = Hsc[e1];
            acc8(a0, w0, s0); acc8(a1, w1, s1);
            sacc += s0 + s1;
        }
        if (k < end) {
            int e0 = esrc[k];
            uint2 w0 = *(const uint2*)(Hb + (size_t)e0 * 128);
            float s0 = Hsc[e0];
            acc8(a0, w0, s0);
            sacc += s0;
        }
        float inv = (end > beg) ? 1.0f / (float)(end - beg) : 0.0f;
        ushort8v mh;
#pragma unroll
        for (int j = 0; j < 8; ++j)
            mh[j] = f2bf((a0[j] + a1[j] - 128.0f * sacc) * inv);
        *(ushort8v*)(&As[0][g16 * PITCH + l16 * 8]) = mh;
    }
    __syncthreads();

    // ---- Phase C: dual GEMM via MFMA over 8 waves (R13-exact) ----
    const int wave = tid >> 6, lane = tid & 63;
    const int rl = lane & 15, quad = lane >> 4;
    const int ct = SPLITRT ? (wave & 3) : wave;   // column tile
    const int rt0 = SPLITRT ? (wave >> 2) : 0;    // first row tile

    f32x4 acc[RTN];
    {
        float bv = bias[ct * 16 + rl];
#pragma unroll
        for (int ri = 0; ri < RTN; ++ri) acc[ri] = (f32x4){bv, bv, bv, bv};
    }

#pragma unroll
    for (int ks = 0; ks < KS; ++ks) {
        short8 a_ag[RTN], a_sh[RTN][2];
#pragma unroll
        for (int ri = 0; ri < RTN; ++ri) {
            int rt = rt0 + ri;
            int off = (rt * 16 + rl) * PITCH + ks * 32 + quad * 8;
            a_ag[ri]    = *(const short8*)(&As[0][off]);
            a_sh[ri][0] = *(const short8*)(&As[1][off]);
            a_sh[ri][1] = *(const short8*)(&As[2][off]);
        }
        size_t boff = (((size_t)ct * KS + ks) * 64 + lane) * 8;
        short8 b1h = *(const short8*)(B1p + boff);
        short8 b1l = *(const short8*)(B1p + HALF + boff);
        short8 b2h = *(const short8*)(B2p + boff);
        short8 b2l = *(const short8*)(B2p + HALF + boff);
#pragma unroll
        for (int ri = 0; ri < RTN; ++ri) {
            acc[ri] = __builtin_amdgcn_mfma_f32_16x16x32_bf16(a_ag[ri],    b1h, acc[ri], 0, 0, 0);
            acc[ri] = __builtin_amdgcn_mfma_f32_16x16x32_bf16(a_ag[ri],    b1l, acc[ri], 0, 0, 0);
            acc[ri] = __builtin_amdgcn_mfma_f32_16x16x32_bf16(a_sh[ri][0], b2h, acc[ri], 0, 0, 0);
            acc[ri] = __builtin_amdgcn_mfma_f32_16x16x32_bf16(a_sh[ri][0], b2l, acc[ri], 0, 0, 0);
            acc[ri] = __builtin_amdgcn_mfma_f32_16x16x32_bf16(a_sh[ri][1], b2h, acc[ri], 0, 0, 0);
        }
    }

    // ---- apply ReLU once, in-register ----
    if (RELU) {
#pragma unroll
        for (int ri = 0; ri < RTN; ++ri)
#pragma unroll
            for (int r = 0; r < 4; ++r)
                acc[ri][r] = fmaxf(acc[ri][r], 0.f);
    }

    float qsc[RTN][4];
    if constexpr (QOUT) {
        float lm[RTN][4];
#pragma unroll
        for (int ri = 0; ri < RTN; ++ri)
#pragma unroll
            for (int r = 0; r < 4; ++r) lm[ri][r] = fabsf(acc[ri][r]);
#pragma unroll
        for (int off = 1; off < 16; off <<= 1)
#pragma unroll
            for (int ri = 0; ri < RTN; ++ri)
#pragma unroll
                for (int r = 0; r < 4; ++r)
                    lm[ri][r] = fmaxf(lm[ri][r], __shfl_xor(lm[ri][r], off));
        if (rl == 0) {
#pragma unroll
            for (int ri = 0; ri < RTN; ++ri)
#pragma unroll
                for (int r = 0; r < 4; ++r)
                    wmax[(rt0 + ri) * 16 + quad * 4 + r][wave] = lm[ri][r];
        }
        __syncthreads();
#pragma unroll
        for (int ri = 0; ri < RTN; ++ri)
#pragma unroll
            for (int r = 0; r < 4; ++r) {
                int row = (rt0 + ri) * 16 + quad * 4 + r;
                float rm = fmaxf(fmaxf(fmaxf(wmax[row][0], wmax[row][1]),
                                       fmaxf(wmax[row][2], wmax[row][3])),
                                 fmaxf(fmaxf(wmax[row][4], wmax[row][5]),
                                       fmaxf(wmax[row][6], wmax[row][7])));
                qsc[ri][r] = rm > 0.f ? 127.0f / rm : 0.0f;
                if (wave == 0 && rl == 0) {
                    int rr = r0 + row;
                    if (rr < M) outsc[rr] = rm * (1.0f / 127.0f);
                }
            }
    }

    // ---- epilogue: C/D layout col=lane&15, row=quad*4+reg ----
#pragma unroll
    for (int ri = 0; ri < RTN; ++ri) {
        int rt = rt0 + ri;
        int col = ct * 16 + rl;
        int rowb = r0 + rt * 16 + quad * 4;
#pragma unroll
        for (int r = 0; r < 4; ++r) {
            int rr = rowb + r;
            if (rr < M) {
                float vv = acc[ri][r];
                outf[(size_t)rr * DOUT + col] = vv;
                if (QOUT) outq[(size_t)rr * DOUT + col] = q8(vv, qsc[ri][r]);
            }
        }
    }
}

// ---------------- launch ----------------

extern "C" void kernel_launch(void* const* d_in, const int* in_sizes, int n_in,
                              void* d_out, int out_size, void* d_ws, size_t ws_size,
                              hipStream_t stream) {
    const float* x   = (const float*)d_in[0];
    const int* eidx  = (const int*)d_in[1];
    const int* src   = eidx;             // edge_index[0]
    const int* dst   = eidx + N_EDGES;   // edge_index[1]
    const float* Wl0 = (const float*)d_in[2];
    const float* b0  = (const float*)d_in[3];
    const float* Wr0 = (const float*)d_in[4];
    const float* Wl1 = (const float*)d_in[5];
    const float* b1  = (const float*)d_in[6];
    const float* Wr1 = (const float*)d_in[7];
    const float* Wl2 = (const float*)d_in[8];
    const float* b2  = (const float*)d_in[9];
    const float* Wr2 = (const float*)d_in[10];
    float* outp = (float*)d_out;

    // workspace (~71 MB): f32 ping-pong h planes + q planes + CSR scratch
    float* hA = (float*)d_ws;                                 // N*128 f32 = 25.6MB
    float* hB = hA + (size_t)N_NODES * 128;                   // N*128 f32
    unsigned int* ebuf = (unsigned int*)hA;                   // ALIAS: NBUCK*BCAPN u32 =
                                                              // 11.0MB <= 25.6MB plane;
                                                              // consumed by fine_fill
                                                              // before layer0 writes hA
    unsigned char* xq = (unsigned char*)(hB + (size_t)N_NODES * 128);  // N*128 u8
    unsigned char* yq = xq + (size_t)N_NODES * 128;
    float* xsc = (float*)(yq + (size_t)N_NODES * 128);        // N f32
    float* ysc = xsc + N_NODES;
    int* rowbeg = (int*)(ysc + N_NODES);                      // N i32
    int* rowend = rowbeg + N_NODES;
    int* cellcnt = rowend + N_NODES;                          // NBUCK*NPART i32 = 306KB
    unsigned short* esrc = (unsigned short*)(cellcnt + NBUCK * NPART); // NBUCK*BCAPN u16 = 5.5MB
    unsigned short* packw = esrc + (size_t)NBUCK * BCAPN;     // 163840 bf16
    unsigned short* Wl0p = packw;
    unsigned short* Wr0p = packw + 32768;
    unsigned short* Wl1p = packw + 65536;
    unsigned short* Wr1p = packw + 98304;
    unsigned short* Wl2p = packw + 131072;
    unsigned short* Wr2p = packw + 147456;

    // --- prep + partition (merged: independent work, one dispatch) ---
    prep_part_kernel<<<1883 + NPART, 256, 0, stream>>>(
        Wl0, Wr0, Wl1, Wr1, Wl2, Wr2, packw, x, xq, xsc,
        src, dst, ebuf, cellcnt);
    // --- per-bucket: rowbeg/rowend + esrc scatter ---
    fine_fill_kernel<<<NBUCK, 256, 0, stream>>>(ebuf, cellcnt, rowbeg, rowend, esrc, N_NODES);

    const int gemmGrid = (N_NODES + 31) / 32;   // 1563

    // layer 0: self=x (input), agg=xq/xsc -> hA (f32) + yq/ysc (ReLU)
    sage_layer<128, true, true><<<gemmGrid, 512, 0, stream>>>(
        xq, xsc, x, rowbeg, rowend, esrc, Wl0p, Wr0p, b0,
        hA, yq, ysc, N_NODES);
    // layer 1: self=hA, agg=yq/ysc -> hB (f32) + xq/xsc (ReLU)
    sage_layer<128, true, true><<<gemmGrid, 512, 0, stream>>>(
        yq, ysc, hA, rowbeg, rowend, esrc, Wl1p, Wr1p, b1,
        hB, xq, xsc, N_NODES);
    // layer 2: self=hB, agg=xq/xsc -> out (f32, no ReLU, DOUT=64)
    sage_layer<64, false, false><<<gemmGrid, 512, 0, stream>>>(
        xq, xsc, hB, rowbeg, rowend, esrc, Wl2p, Wr2p, b2,
        outp, nullptr, nullptr, N_NODES);
}